// Round 1
// baseline (418.441 us; speedup 1.0000x reference)
//
#include <hip/hip_runtime.h>
#include <hip/hip_bf16.h>

// Problem constants (match setup_inputs): B=8, F=64, E=50000, Cout=128, K=5
#define NB 8
#define NF 64
#define NE 50000
#define NO 128
#define TE 64              // e-tile per block in main kernel
#define NK 320             // K' = 5*64 combined contraction dim
#define KSTEPS 10          // 320 / 32

typedef short short8 __attribute__((ext_vector_type(8)));
typedef float f32x4 __attribute__((ext_vector_type(4)));

__device__ __forceinline__ unsigned short f2bf(float x) {
    union { float f; unsigned int u; } v; v.f = x;
    unsigned int r = v.u + 0x7fffu + ((v.u >> 16) & 1u);
    return (unsigned short)(r >> 16);
}

// ---------------------------------------------------------------------------
// Kernel 1: transpose x (B,F,E) -> xT (B,E,F) so gathers become contiguous.
// ---------------------------------------------------------------------------
__global__ __launch_bounds__(256) void transpose_x(
    const float* __restrict__ x, float* __restrict__ xT, int E)
{
    __shared__ float tile[64][65];  // +1 pad: conflict-free transpose
    int ntiles = (E + 63) >> 6;
    int b = blockIdx.x / ntiles;
    int t = blockIdx.x % ntiles;
    int e0 = t << 6;
    int le = threadIdx.x & 63;
    int q  = threadIdx.x >> 6;     // 0..3
    const float* xb = x + (size_t)b * NF * E;
    #pragma unroll
    for (int i = 0; i < 16; ++i) {
        int f = q * 16 + i;
        int e = e0 + le;
        tile[f][le] = (e < E) ? xb[(size_t)f * E + e] : 0.0f;
    }
    __syncthreads();
    float* xTb = xT + (size_t)b * E * NF;
    #pragma unroll
    for (int i = 0; i < 16; ++i) {
        int el = q * 16 + i;
        int e = e0 + el;
        if (e < E) xTb[(size_t)e * NF + le] = tile[le][el];
    }
}

// ---------------------------------------------------------------------------
// Kernel 2: repack W (Cout,F,1,K) fp32 -> Wt bf16 in MFMA A-frag order:
//   K' = kp*64 + f ; layout Wt[kblk=K'/8][o=128][slot=K'%8]
// ---------------------------------------------------------------------------
__global__ __launch_bounds__(256) void prep_w(
    const float* __restrict__ W, unsigned short* __restrict__ Wt)
{
    int idx = blockIdx.x * 256 + threadIdx.x;   // 320*128 = 40960 total
    if (idx >= NK * NO) return;
    int K = idx >> 7;       // 0..319
    int o = idx & 127;
    int f  = K & 63;
    int kp = K >> 6;
    float v = W[(size_t)o * (NF * 5) + f * 5 + kp];
    Wt[((size_t)(K >> 3) * NO + o) * 8 + (K & 7)] = f2bf(v);
}

// ---------------------------------------------------------------------------
// Kernel 3: main fused gather + combine + MFMA GEMM.
// Block = 256 threads (4 waves), handles one (b, 64-e tile).
// Phase A: build bf16 G in LDS, layout Gs[kblk=40][e=64][slot=8].
// Phase B: 16x16x32 bf16 MFMA; each wave: 4 M-tiles x 2 N-tiles, 10 K-steps.
// ---------------------------------------------------------------------------
__global__ __launch_bounds__(256) void conv_main(
    const float* __restrict__ xsrc,   // xT (B,E,F) if useXT else x (B,F,E)
    const int* __restrict__ gemm,     // (B,E,4) int32
    const unsigned short* __restrict__ Wt,
    const float* __restrict__ bias,
    float* __restrict__ out,          // (B,128,E)
    int E, int useXT)
{
    __shared__ __align__(16) unsigned short Gs[NK * TE]; // 40 KB

    int ntiles = (E + TE - 1) / TE;
    int b     = blockIdx.x / ntiles;
    int etile = blockIdx.x % ntiles;
    int tid = threadIdx.x;

    // ---- Phase A: gather 5 columns per e, combine, write bf16 G ----
    {
        int ge = tid >> 2;        // 0..63 : e within tile
        int j  = tid & 3;         // f-quarter (16 f each)
        int e  = etile * TE + ge;
        bool valid = (e < E);
        int gi[5];
        if (valid) {
            gi[0] = e;
            const int* gp = gemm + ((size_t)b * E + e) * 4;
            gi[1] = gp[0]; gi[2] = gp[1]; gi[3] = gp[2]; gi[4] = gp[3];
        }
        #pragma unroll
        for (int h = 0; h < 2; ++h) {
            int f0 = j * 16 + h * 8;
            float c[5][8];
            if (valid) {
                if (useXT) {
                    #pragma unroll
                    for (int k = 0; k < 5; ++k) {
                        const float* p = xsrc + ((size_t)b * E + gi[k]) * NF + f0;
                        float4 v0 = *(const float4*)p;
                        float4 v1 = *(const float4*)(p + 4);
                        c[k][0] = v0.x; c[k][1] = v0.y; c[k][2] = v0.z; c[k][3] = v0.w;
                        c[k][4] = v1.x; c[k][5] = v1.y; c[k][6] = v1.z; c[k][7] = v1.w;
                    }
                } else {
                    #pragma unroll
                    for (int k = 0; k < 5; ++k)
                        #pragma unroll
                        for (int i = 0; i < 8; ++i)
                            c[k][i] = xsrc[(size_t)b * NF * E + (size_t)(f0 + i) * E + gi[k]];
                }
            } else {
                #pragma unroll
                for (int k = 0; k < 5; ++k)
                    #pragma unroll
                    for (int i = 0; i < 8; ++i) c[k][i] = 0.0f;
            }
            float g[5][8];
            #pragma unroll
            for (int i = 0; i < 8; ++i) {
                g[0][i] = c[0][i];
                g[1][i] = c[1][i] + c[3][i];
                g[2][i] = c[2][i] + c[4][i];
                g[3][i] = fabsf(c[1][i] - c[3][i]);
                g[4][i] = fabsf(c[2][i] - c[4][i]);
            }
            #pragma unroll
            for (int kp = 0; kp < 5; ++kp) {
                int kblk = kp * 8 + j * 2 + h;   // K' = kp*64 + f0.. : one full kblk row
                uint4 pk;
                pk.x = (unsigned)f2bf(g[kp][0]) | ((unsigned)f2bf(g[kp][1]) << 16);
                pk.y = (unsigned)f2bf(g[kp][2]) | ((unsigned)f2bf(g[kp][3]) << 16);
                pk.z = (unsigned)f2bf(g[kp][4]) | ((unsigned)f2bf(g[kp][5]) << 16);
                pk.w = (unsigned)f2bf(g[kp][6]) | ((unsigned)f2bf(g[kp][7]) << 16);
                *(uint4*)&Gs[((size_t)kblk * TE + ge) * 8] = pk;
            }
        }
    }
    __syncthreads();

    // ---- Phase B: MFMA ----
    int wave = tid >> 6;
    int lane = tid & 63;
    int l16 = lane & 15;
    int lq  = lane >> 4;            // 0..3
    int mh = (wave >> 1) * 4;       // M-tile base (4 tiles of 16 -> 64 o rows)
    int np = (wave & 1) * 2;        // N-tile base (2 tiles of 16 -> 32 e cols)

    f32x4 acc[4][2];
    #pragma unroll
    for (int mt = 0; mt < 4; ++mt)
        #pragma unroll
        for (int nt = 0; nt < 2; ++nt)
            acc[mt][nt] = (f32x4){0.f, 0.f, 0.f, 0.f};

    for (int ks = 0; ks < KSTEPS; ++ks) {
        short8 a[4], bb[2];
        #pragma unroll
        for (int mt = 0; mt < 4; ++mt) {
            int o = (mh + mt) * 16 + l16;
            a[mt] = *(const short8*)&Wt[((size_t)(ks * 4 + lq) * NO + o) * 8];
        }
        #pragma unroll
        for (int nt = 0; nt < 2; ++nt) {
            int el = (np + nt) * 16 + l16;
            bb[nt] = *(const short8*)&Gs[((size_t)(ks * 4 + lq) * TE + el) * 8];
        }
        #pragma unroll
        for (int mt = 0; mt < 4; ++mt)
            #pragma unroll
            for (int nt = 0; nt < 2; ++nt)
                acc[mt][nt] = __builtin_amdgcn_mfma_f32_16x16x32_bf16(
                    a[mt], bb[nt], acc[mt][nt], 0, 0, 0);
    }

    // ---- Epilogue: C layout col=lane&15 (e), row=(lane>>4)*4+reg (o) ----
    #pragma unroll
    for (int mt = 0; mt < 4; ++mt) {
        #pragma unroll
        for (int nt = 0; nt < 2; ++nt) {
            int el = (np + nt) * 16 + l16;
            int e  = etile * TE + el;
            if (e < E) {
                #pragma unroll
                for (int r = 0; r < 4; ++r) {
                    int o = (mh + mt) * 16 + lq * 4 + r;
                    out[((size_t)b * NO + o) * E + e] = acc[mt][nt][r] + bias[o];
                }
            }
        }
    }
}

extern "C" void kernel_launch(void* const* d_in, const int* in_sizes, int n_in,
                              void* d_out, int out_size, void* d_ws, size_t ws_size,
                              hipStream_t stream)
{
    const float* x    = (const float*)d_in[0];
    const int*   gemm = (const int*)d_in[1];
    const float* W    = (const float*)d_in[2];
    const float* bias = (const float*)d_in[3];
    float* out = (float*)d_out;

    const int E = NE;
    unsigned short* Wt = (unsigned short*)d_ws;           // 81,920 B
    size_t xT_off = 131072;                               // 128 KB aligned region
    float* xT = (float*)((char*)d_ws + xT_off);
    size_t need = xT_off + (size_t)NB * E * NF * sizeof(float);
    int useXT = (ws_size >= need) ? 1 : 0;

    prep_w<<<(NK * NO + 255) / 256, 256, 0, stream>>>(W, Wt);

    int ntiles = (E + TE - 1) / TE;   // 782
    if (useXT)
        transpose_x<<<NB * ntiles, 256, 0, stream>>>(x, xT, E);

    conv_main<<<NB * ntiles, 256, 0, stream>>>(
        useXT ? xT : x, gemm, Wt, bias, out, E, useXT);
}

// Round 3
// 413.772 us; speedup vs baseline: 1.0113x; 1.0113x over previous
//
#include <hip/hip_runtime.h>
#include <hip/hip_bf16.h>

// Problem constants (match setup_inputs): B=8, F=64, E=50000, Cout=128, K=5
#define NB 8
#define NF 64
#define NE 50000
#define NO 128
#define NK 320             // K' = 5*64 combined contraction dim

typedef short short8 __attribute__((ext_vector_type(8)));
typedef float f32x4 __attribute__((ext_vector_type(4)));

__device__ __forceinline__ unsigned short f2bf(float x) {
    // round-to-nearest-even bf16 conversion (bit trick; matches hardware cvt)
    union { float f; unsigned int u; } v; v.f = x;
    unsigned int r = v.u + 0x7fffu + ((v.u >> 16) & 1u);
    return (unsigned short)(r >> 16);
}
__device__ __forceinline__ float bf2f(unsigned short h) {
    union { unsigned int u; float f; } v; v.u = ((unsigned int)h) << 16; return v.f;
}

// ---------------------------------------------------------------------------
// Kernel 1: transpose x (B,F,E) fp32 -> xT (B,E,F) bf16 (contiguous gathers).
// ---------------------------------------------------------------------------
__global__ __launch_bounds__(256) void transpose_x(
    const float* __restrict__ x, unsigned short* __restrict__ xT, int E)
{
    __shared__ float tile[64][65];  // +1 pad: conflict-free transpose
    int ntiles = (E + 63) >> 6;
    int b = blockIdx.x / ntiles;
    int t = blockIdx.x % ntiles;
    int e0 = t << 6;
    int le = threadIdx.x & 63;
    int q  = threadIdx.x >> 6;     // 0..3
    const float* xb = x + (size_t)b * NF * E;
    #pragma unroll
    for (int i = 0; i < 16; ++i) {
        int f = q * 16 + i;
        int e = e0 + le;
        tile[f][le] = (e < E) ? xb[(size_t)f * E + e] : 0.0f;
    }
    __syncthreads();
    unsigned short* xTb = xT + (size_t)b * E * NF;
    int fp = (threadIdx.x & 31) * 2;   // even f
    int es = threadIdx.x >> 5;         // 0..7
    #pragma unroll
    for (int i = 0; i < 8; ++i) {
        int el = i * 8 + es;
        int e = e0 + el;
        if (e < E) {
            unsigned int pk = (unsigned int)f2bf(tile[fp][el])
                            | ((unsigned int)f2bf(tile[fp + 1][el]) << 16);
            *(unsigned int*)&xTb[(size_t)e * NF + fp] = pk;
        }
    }
}

// ---------------------------------------------------------------------------
// Kernel 2: repack W (Cout,F,1,K) fp32 -> Wt bf16 in MFMA A-frag order:
//   K' = kp*64 + f ; layout Wt[kblk=K'/8][o=128][slot=K'%8]
// ---------------------------------------------------------------------------
__global__ __launch_bounds__(256) void prep_w(
    const float* __restrict__ W, unsigned short* __restrict__ Wt)
{
    int idx = blockIdx.x * 256 + threadIdx.x;   // 320*128 = 40960 total
    if (idx >= NK * NO) return;
    int K = idx >> 7;       // 0..319
    int o = idx & 127;
    int f  = K & 63;
    int kp = K >> 6;
    float v = W[(size_t)o * (NF * 5) + f * 5 + kp];
    Wt[((size_t)(K >> 3) * NO + o) * 8 + (K & 7)] = f2bf(v);
}

// ---------------------------------------------------------------------------
// Kernel 3: fused gather + combine + MFMA, fully in registers (no LDS).
// Block = 256 threads (4 waves), NO barrier. Each wave owns 16 e-nodes
// (its N-tile) and all 128 output channels (8 M-tiles of 16).
// B-frag insight: lane(l16,lq) needs G[f=f0+lq*8..+8] at node e=l16 —
// exactly one contiguous bf16x8 slice of a gathered xT row.
// ---------------------------------------------------------------------------
__global__ __launch_bounds__(256) void conv_main(
    const unsigned short* __restrict__ xT,   // (B,E,64) bf16
    const int* __restrict__ gemm,            // (B,E,4) int32
    const unsigned short* __restrict__ Wt,   // [40][128][8] bf16
    const float* __restrict__ bias,
    float* __restrict__ out,                 // (B,128,E) fp32
    int E)
{
    int ntiles = (E + 63) >> 6;
    int b     = blockIdx.x / ntiles;
    int etile = blockIdx.x % ntiles;
    int tid  = threadIdx.x;
    int wave = tid >> 6;
    int lane = tid & 63;
    int l16  = lane & 15;
    int lq   = lane >> 4;           // 0..3

    int e = etile * 64 + wave * 16 + l16;
    bool valid = (e < E);
    int eC = valid ? e : (E - 1);   // clamp for safe addressing; result discarded

    int gi[5];
    gi[0] = eC;
    int4 gv = *(const int4*)(gemm + ((size_t)b * E + eC) * 4);
    gi[1] = gv.x; gi[2] = gv.y; gi[3] = gv.z; gi[4] = gv.w;

    f32x4 acc[8];
    #pragma unroll
    for (int mt = 0; mt < 8; ++mt) acc[mt] = (f32x4){0.f, 0.f, 0.f, 0.f};

    const unsigned short* xb = xT + (size_t)b * E * NF;

    #pragma unroll
    for (int half = 0; half < 2; ++half) {
        int f0 = half * 32 + lq * 8;
        // gather 5 bf16x8 slices (16B each, 16 rows x 64B per wave-instr)
        uint4 craw[5];
        #pragma unroll
        for (int k = 0; k < 5; ++k)
            craw[k] = *(const uint4*)&xb[(size_t)gi[k] * NF + f0];

        const unsigned short* c1 = (const unsigned short*)&craw[1];
        const unsigned short* c2 = (const unsigned short*)&craw[2];
        const unsigned short* c3 = (const unsigned short*)&craw[3];
        const unsigned short* c4 = (const unsigned short*)&craw[4];

        short8 g[5];
        g[0] = *(short8*)&craw[0];                 // x0 passthrough (already bf16)
        unsigned short gb[4][8];
        #pragma unroll
        for (int i = 0; i < 8; ++i) {
            float a1 = bf2f(c1[i]), a2 = bf2f(c2[i]);
            float a3 = bf2f(c3[i]), a4 = bf2f(c4[i]);
            gb[0][i] = f2bf(a1 + a3);
            gb[1][i] = f2bf(a2 + a4);
            gb[2][i] = f2bf(fabsf(a1 - a3));
            gb[3][i] = f2bf(fabsf(a2 - a4));
        }
        g[1] = *(short8*)&gb[0][0];
        g[2] = *(short8*)&gb[1][0];
        g[3] = *(short8*)&gb[2][0];
        g[4] = *(short8*)&gb[3][0];

        #pragma unroll
        for (int kp = 0; kp < 5; ++kp) {
            int ks = kp * 2 + half;                // K-step 0..9
            const unsigned short* wp = Wt + (size_t)(ks * 4 + lq) * NO * 8;
            #pragma unroll
            for (int mt = 0; mt < 8; ++mt) {
                short8 a = *(const short8*)&wp[(mt * 16 + l16) * 8];
                acc[mt] = __builtin_amdgcn_mfma_f32_16x16x32_bf16(a, g[kp], acc[mt], 0, 0, 0);
            }
        }
    }

    // Epilogue: C layout col(e)=lane&15, row(o)=(lane>>4)*4+reg
    if (valid) {
        #pragma unroll
        for (int mt = 0; mt < 8; ++mt) {
            #pragma unroll
            for (int r = 0; r < 4; ++r) {
                int o = mt * 16 + lq * 4 + r;
                out[((size_t)b * NO + o) * E + e] = acc[mt][r] + bias[o];
            }
        }
    }
}

extern "C" void kernel_launch(void* const* d_in, const int* in_sizes, int n_in,
                              void* d_out, int out_size, void* d_ws, size_t ws_size,
                              hipStream_t stream)
{
    const float* x    = (const float*)d_in[0];
    const int*   gemm = (const int*)d_in[1];
    const float* W    = (const float*)d_in[2];
    const float* bias = (const float*)d_in[3];
    float* out = (float*)d_out;

    const int E = NE;
    unsigned short* Wt = (unsigned short*)d_ws;            // 81,920 B
    unsigned short* xT = (unsigned short*)((char*)d_ws + 131072); // bf16, 51.2 MB

    prep_w<<<(NK * NO + 255) / 256, 256, 0, stream>>>(W, Wt);

    int ntiles = (E + 63) / 64;   // 782
    transpose_x<<<NB * ntiles, 256, 0, stream>>>(x, xT, E);

    conv_main<<<NB * ntiles, 256, 0, stream>>>(xT, gemm, Wt, bias, out, E);
}

// Round 4
// 372.880 us; speedup vs baseline: 1.1222x; 1.1097x over previous
//
#include <hip/hip_runtime.h>
#include <hip/hip_bf16.h>

// Problem constants (match setup_inputs): B=8, F=64, E=50000, Cout=128, K=5
#define NB 8
#define NF 64
#define NE 50000
#define NO 128
#define NK 320             // K' = 5*64 combined contraction dim
#define CONV_GRID 768      // persistent blocks (3 per CU)

typedef short short8 __attribute__((ext_vector_type(8)));
typedef float f32x4 __attribute__((ext_vector_type(4)));

__device__ __forceinline__ unsigned short f2bf(float x) {
    // round-to-nearest-even bf16 conversion (bit trick; matches hardware cvt)
    union { float f; unsigned int u; } v; v.f = x;
    unsigned int r = v.u + 0x7fffu + ((v.u >> 16) & 1u);
    return (unsigned short)(r >> 16);
}
__device__ __forceinline__ float bf2f(unsigned short h) {
    union { unsigned int u; float f; } v; v.u = ((unsigned int)h) << 16; return v.f;
}

// ---------------------------------------------------------------------------
// Kernel 1: transpose x (B,F,E) fp32 -> xT (B,E,F) bf16 (contiguous gathers).
// ---------------------------------------------------------------------------
__global__ __launch_bounds__(256) void transpose_x(
    const float* __restrict__ x, unsigned short* __restrict__ xT, int E)
{
    __shared__ float tile[64][65];  // +1 pad: conflict-free transpose
    int ntiles = (E + 63) >> 6;
    int b = blockIdx.x / ntiles;
    int t = blockIdx.x % ntiles;
    int e0 = t << 6;
    int le = threadIdx.x & 63;
    int q  = threadIdx.x >> 6;     // 0..3
    const float* xb = x + (size_t)b * NF * E;
    #pragma unroll
    for (int i = 0; i < 16; ++i) {
        int f = q * 16 + i;
        int e = e0 + le;
        tile[f][le] = (e < E) ? xb[(size_t)f * E + e] : 0.0f;
    }
    __syncthreads();
    unsigned short* xTb = xT + (size_t)b * E * NF;
    int fp = (threadIdx.x & 31) * 2;   // even f
    int es = threadIdx.x >> 5;         // 0..7
    #pragma unroll
    for (int i = 0; i < 8; ++i) {
        int el = i * 8 + es;
        int e = e0 + el;
        if (e < E) {
            unsigned int pk = (unsigned int)f2bf(tile[fp][el])
                            | ((unsigned int)f2bf(tile[fp + 1][el]) << 16);
            *(unsigned int*)&xTb[(size_t)e * NF + fp] = pk;
        }
    }
}

// ---------------------------------------------------------------------------
// Kernel 2: repack W (Cout,F,1,K) fp32 -> Wt bf16 in MFMA A-frag order:
//   K' = kp*64 + f ; layout Wt[kblk=K'/8][o=128][slot=K'%8]
// ---------------------------------------------------------------------------
__global__ __launch_bounds__(256) void prep_w(
    const float* __restrict__ W, unsigned short* __restrict__ Wt)
{
    int idx = blockIdx.x * 256 + threadIdx.x;   // 320*128 = 40960 total
    if (idx >= NK * NO) return;
    int K = idx >> 7;       // 0..319
    int o = idx & 127;
    int f  = K & 63;
    int kp = K >> 6;
    float v = W[(size_t)o * (NF * 5) + f * 5 + kp];
    Wt[((size_t)(K >> 3) * NO + o) * 8 + (K & 7)] = f2bf(v);
}

// ---------------------------------------------------------------------------
// Kernel 3: persistent fused gather + combine + MFMA.
// Grid = CONV_GRID blocks x 256 threads (4 waves), grid-stride over
// 6256 (b, e-tile) units. Each wave owns 2 M-tiles (32 of 128 channels);
// its W fragments (80 VGPRs) are loaded ONCE per block lifetime — this
// removes the 80 KB/wave W re-read stream that bound rounds 1-3.
// Per unit: phase A builds bf16 G for 64 e in LDS cooperatively (combine
// done once), barrier, phase B: each wave ds_reads B-frags (shared by its
// 2 M-tiles) and MFMAs, then stores.
// ---------------------------------------------------------------------------
__global__ __launch_bounds__(256) void conv_main(
    const unsigned short* __restrict__ xT,   // (B,E,64) bf16
    const int* __restrict__ gemm,            // (B,E,4) int32
    const unsigned short* __restrict__ Wt,   // [40][128][8] bf16
    const float* __restrict__ bias,
    float* __restrict__ out,                 // (B,128,E) fp32
    int E)
{
    __shared__ __align__(16) unsigned short Gs[40 * 64 * 8]; // 40 KB

    int tid  = threadIdx.x;
    int wave = tid >> 6;
    int lane = tid & 63;
    int l16  = lane & 15;
    int lq   = lane >> 4;           // 0..3

    // ---- persistent per-wave state: W frags + bias (loaded once) ----
    short8 wfrag[10][2];
    #pragma unroll
    for (int ks = 0; ks < 10; ++ks)
        #pragma unroll
        for (int m = 0; m < 2; ++m) {
            int o = (wave * 2 + m) * 16 + l16;
            wfrag[ks][m] = *(const short8*)&Wt[((size_t)(ks * 4 + lq) * NO + o) * 8];
        }
    float biasr[2][4];
    #pragma unroll
    for (int m = 0; m < 2; ++m)
        #pragma unroll
        for (int r = 0; r < 4; ++r)
            biasr[m][r] = bias[(wave * 2 + m) * 16 + lq * 4 + r];

    int ntiles = (E + 63) >> 6;
    int nunits = NB * ntiles;
    int ge = tid >> 2;              // 0..63 : e within tile (phase A role)
    int j  = tid & 3;               // f-quarter (phase A role)

    for (int unit = blockIdx.x; unit < nunits; unit += gridDim.x) {
        int b     = unit / ntiles;
        int etile = unit % ntiles;

        // ---- Phase A: gather + combine + pack into LDS ----
        {
            int e  = etile * 64 + ge;
            int eC = (e < E) ? e : (E - 1);   // clamp; garbage cols discarded at store
            const unsigned short* xb = xT + (size_t)b * E * NF;
            int4 gv = *(const int4*)(gemm + ((size_t)b * E + eC) * 4);
            int gi[5];
            gi[0] = eC; gi[1] = gv.x; gi[2] = gv.y; gi[3] = gv.z; gi[4] = gv.w;

            #pragma unroll
            for (int half = 0; half < 2; ++half) {
                int f0 = half * 32 + j * 8;
                uint4 craw[5];
                #pragma unroll
                for (int k = 0; k < 5; ++k)
                    craw[k] = *(const uint4*)&xb[(size_t)gi[k] * NF + f0];

                const unsigned short* c1 = (const unsigned short*)&craw[1];
                const unsigned short* c2 = (const unsigned short*)&craw[2];
                const unsigned short* c3 = (const unsigned short*)&craw[3];
                const unsigned short* c4 = (const unsigned short*)&craw[4];

                uint4 pk[5];
                pk[0] = craw[0];                      // x0 passthrough
                unsigned short gb[4][8];
                #pragma unroll
                for (int i = 0; i < 8; ++i) {
                    float a1 = bf2f(c1[i]), a2 = bf2f(c2[i]);
                    float a3 = bf2f(c3[i]), a4 = bf2f(c4[i]);
                    gb[0][i] = f2bf(a1 + a3);
                    gb[1][i] = f2bf(a2 + a4);
                    gb[2][i] = f2bf(fabsf(a1 - a3));
                    gb[3][i] = f2bf(fabsf(a2 - a4));
                }
                pk[1] = *(uint4*)&gb[0][0];
                pk[2] = *(uint4*)&gb[1][0];
                pk[3] = *(uint4*)&gb[2][0];
                pk[4] = *(uint4*)&gb[3][0];

                #pragma unroll
                for (int kp = 0; kp < 5; ++kp) {
                    int kblk = kp * 8 + half * 4 + j;   // K-block 0..39
                    *(uint4*)&Gs[((size_t)kblk * 64 + ge) * 8] = pk[kp];
                }
            }
        }
        __syncthreads();

        // ---- Phase B: MFMA (W from regs, B from LDS) ----
        f32x4 acc[2][4];
        #pragma unroll
        for (int m = 0; m < 2; ++m)
            #pragma unroll
            for (int nt = 0; nt < 4; ++nt)
                acc[m][nt] = (f32x4){0.f, 0.f, 0.f, 0.f};

        #pragma unroll
        for (int ks = 0; ks < 10; ++ks) {
            short8 bb[4];
            #pragma unroll
            for (int nt = 0; nt < 4; ++nt)
                bb[nt] = *(const short8*)&Gs[(((size_t)(ks * 4 + lq)) * 64 + nt * 16 + l16) * 8];
            #pragma unroll
            for (int m = 0; m < 2; ++m)
                #pragma unroll
                for (int nt = 0; nt < 4; ++nt)
                    acc[m][nt] = __builtin_amdgcn_mfma_f32_16x16x32_bf16(
                        wfrag[ks][m], bb[nt], acc[m][nt], 0, 0, 0);
        }

        // ---- Epilogue: C layout col(e)=lane&15, row(o)=(lane>>4)*4+reg ----
        int e0 = etile * 64;
        #pragma unroll
        for (int m = 0; m < 2; ++m) {
            #pragma unroll
            for (int nt = 0; nt < 4; ++nt) {
                int e = e0 + nt * 16 + l16;
                if (e < E) {
                    #pragma unroll
                    for (int r = 0; r < 4; ++r) {
                        int o = (wave * 2 + m) * 16 + lq * 4 + r;
                        out[((size_t)b * NO + o) * E + e] = acc[m][nt][r] + biasr[m][r];
                    }
                }
            }
        }
        __syncthreads();   // protect Gs before next iteration's phase A
    }
}

extern "C" void kernel_launch(void* const* d_in, const int* in_sizes, int n_in,
                              void* d_out, int out_size, void* d_ws, size_t ws_size,
                              hipStream_t stream)
{
    const float* x    = (const float*)d_in[0];
    const int*   gemm = (const int*)d_in[1];
    const float* W    = (const float*)d_in[2];
    const float* bias = (const float*)d_in[3];
    float* out = (float*)d_out;

    const int E = NE;
    unsigned short* Wt = (unsigned short*)d_ws;            // 81,920 B
    unsigned short* xT = (unsigned short*)((char*)d_ws + 131072); // bf16, 51.2 MB

    prep_w<<<(NK * NO + 255) / 256, 256, 0, stream>>>(W, Wt);

    int ntiles = (E + 63) / 64;   // 782
    transpose_x<<<NB * ntiles, 256, 0, stream>>>(x, xT, E);

    conv_main<<<CONV_GRID, 256, 0, stream>>>(xT, gemm, Wt, bias, out, E);
}